// Round 3
// baseline (1270.315 us; speedup 1.0000x reference)
//
#include <hip/hip_runtime.h>
#include <hip/hip_bf16.h>
#include <stdint.h>

typedef __hip_bfloat16 bf16;
typedef unsigned short u16;
typedef unsigned int u32;
using short8  = __attribute__((ext_vector_type(8))) short;
using short4v = __attribute__((ext_vector_type(4))) short;
using floatx4 = __attribute__((ext_vector_type(4))) float;
using uintx4  = __attribute__((ext_vector_type(4))) u32;

#define LOG2E 1.44269504088896f

__device__ __forceinline__ float b2f(u16 u) {
  union { u32 i; float f; } v; v.i = ((u32)u) << 16; return v.f;
}
__device__ __forceinline__ u16 f2b(float f) {
  union { float f; u32 i; } v; v.f = f;
  u32 r = v.i + 0x7fffu + ((v.i >> 16) & 1u);
  return (u16)(r >> 16);
}

// ------------------------------------------------ fp32 -> bf16 weight convert
// grid (256, 4): y selects which 512x512 matrix; x*256 threads * 4 elems
__global__ __launch_bounds__(256)
void cvt_weights(const float* __restrict__ w0, const float* __restrict__ w1,
                 const float* __restrict__ w2, const float* __restrict__ w3,
                 u16* __restrict__ o0, u16* __restrict__ o1,
                 u16* __restrict__ o2, u16* __restrict__ o3)
{
  const float* w = blockIdx.y == 0 ? w0 : blockIdx.y == 1 ? w1 : blockIdx.y == 2 ? w2 : w3;
  u16* o = blockIdx.y == 0 ? o0 : blockIdx.y == 1 ? o1 : blockIdx.y == 2 ? o2 : o3;
  const int i = (blockIdx.x * 256 + threadIdx.x) * 4;
  floatx4 v = *(const floatx4*)(w + i);
  short4v p;
#pragma unroll
  for (int j = 0; j < 4; j++) p[j] = (short)f2b(v[j]);
  *(short4v*)(o + i) = p;
}

// ---------------------------------------------------------------- GroupNorm
// one block per (group, batch): mean/rstd over 64 ch x 4096 px = 262144 fp32
__global__ __launch_bounds__(256)
void gn_stats(const float* __restrict__ x, float* __restrict__ gmean, float* __restrict__ grstd)
{
  const int g = blockIdx.x, b = blockIdx.y;
  const float* base = x + ((long)(b * 512 + g * 64)) * 4096;
  const int t = threadIdx.x;
  float s = 0.f, ss = 0.f;
  for (int i = 0; i < 256; i++) {
    floatx4 v = *(const floatx4*)(base + i * 1024 + t * 4);
#pragma unroll
    for (int j = 0; j < 4; j++) { s += v[j]; ss += v[j] * v[j]; }
  }
  for (int off = 1; off < 64; off <<= 1) {
    s  += __shfl_xor(s, off, 64);
    ss += __shfl_xor(ss, off, 64);
  }
  __shared__ float as_[4], ass_[4];
  if ((t & 63) == 0) { as_[t >> 6] = s; ass_[t >> 6] = ss; }
  __syncthreads();
  if (t == 0) {
    float S1 = as_[0] + as_[1] + as_[2] + as_[3];
    float S2 = ass_[0] + ass_[1] + ass_[2] + ass_[3];
    const float inv = 1.0f / 262144.0f;
    float mu = S1 * inv;
    float var = S2 * inv - mu * mu;
    gmean[b * 8 + g] = mu;
    grstd[b * 8 + g] = rsqrtf(var + 1e-5f);
  }
}

// normalize + transpose: x[b][c][p] (fp32) -> h[b][p][c] (bf16); b chunk-local
__global__ __launch_bounds__(256)
void gn_apply(const float* __restrict__ x, const float* __restrict__ gw, const float* __restrict__ gb,
              const float* __restrict__ gmean, const float* __restrict__ grstd,
              bf16* __restrict__ h)
{
  const int b = blockIdx.z;
  const int c0 = blockIdx.y * 64;
  const int p0 = blockIdx.x * 64;
  const int t = threadIdx.x;
  const int c = c0 + (t & 63);
  const int g = c >> 6;
  const float mu = gmean[b * 8 + g], rs = grstd[b * 8 + g];
  const float wv = gw[c];
  const float bv = gb[c];
  const float a = rs * wv;
  const float bb = bv - mu * rs * wv;
  const float* xp = x + ((long)(b * 512 + c)) * 4096;
  u16* hp = (u16*)h + ((long)b * 4096) * 512 + c;
  const int pbase = p0 + (t >> 6);
#pragma unroll
  for (int i = 0; i < 16; i++) {
    int p = pbase + i * 4;
    float xv = xp[p];
    hp[(long)p * 512] = f2b(xv * a + bb);
  }
}

// ---------------------------------------------------------------- row softmax stats
__global__ __launch_bounds__(256)
void row_stats(const bf16* __restrict__ S, float* __restrict__ mrow, float* __restrict__ rl)
{
  const long row = blockIdx.x;
  const int t = threadIdx.x;
  const u16* Sr = (const u16*)S + row * 4096;
  uintx4 v0 = *(const uintx4*)(Sr + t * 16);
  uintx4 v1 = *(const uintx4*)(Sr + t * 16 + 8);
  float vals[16];
#pragma unroll
  for (int i = 0; i < 4; i++) {
    vals[2 * i]     = b2f((u16)(v0[i] & 0xffffu));
    vals[2 * i + 1] = b2f((u16)(v0[i] >> 16));
    vals[8 + 2 * i]     = b2f((u16)(v1[i] & 0xffffu));
    vals[8 + 2 * i + 1] = b2f((u16)(v1[i] >> 16));
  }
  float m = vals[0];
#pragma unroll
  for (int i = 1; i < 16; i++) m = fmaxf(m, vals[i]);
  for (int off = 1; off < 64; off <<= 1) m = fmaxf(m, __shfl_xor(m, off, 64));
  __shared__ float sm[4], st[4];
  if ((t & 63) == 0) sm[t >> 6] = m;
  __syncthreads();
  m = fmaxf(fmaxf(sm[0], sm[1]), fmaxf(sm[2], sm[3]));
  float s = 0.f;
#pragma unroll
  for (int i = 0; i < 16; i++) s += exp2f((vals[i] - m) * LOG2E);
  for (int off = 1; off < 64; off <<= 1) s += __shfl_xor(s, off, 64);
  if ((t & 63) == 0) st[t >> 6] = s;
  __syncthreads();
  if (t == 0) {
    float tot = st[0] + st[1] + st[2] + st[3];
    mrow[row] = m;
    rl[row] = 1.0f / tot;
  }
}

// ---------------------------------------------------------------- GEMM: C = A @ B^T (+bias etc.)
// A,B are bf16. bias/resid fp32.
// MODE 0: +bias, write bf16 out[m][n]                  (Q, K)
// MODE 1: +bias, write bf16 out[n][m]                  (V -> vT)
// MODE 2: *1/sqrt(512), write bf16 out[m][n]           (S = q k^T)
// MODE 3: A-staging applies exp(s-m); epilogue *1/l    (O = P V, bf16)
// MODE 4: +bias + residual, write FP32 out[n][m]       (final proj + x)
constexpr int BM = 128, BN = 128, BK = 32;
constexpr int LDT = BK + 8;   // padded LDS row (bf16 elems)

template<int MODE>
__global__ __launch_bounds__(256)
void gemm_bt(const bf16* __restrict__ Ag, long sA,
             const bf16* __restrict__ Bg, long sB,
             const float* __restrict__ bias,
             const float* __restrict__ mrow,
             const float* __restrict__ rlrow,
             const float* __restrict__ resid, long sR,
             bf16* __restrict__ Og, long sO,
             int M, int N, int K)
{
  __shared__ u16 As[BM * LDT];
  __shared__ u16 Bs[BN * LDT];
  const int t = threadIdx.x;
  const int bz = blockIdx.z;
  const bf16* A = Ag + (long)bz * sA;
  const bf16* Bm = Bg + (long)bz * sB;

  const int bm = blockIdx.x, bn = blockIdx.y;
  const int r = t >> 1;             // 0..127 (staging row)
  const int seg = (t & 1) * 16;     // 0 / 16
  const long aRow = (long)(bm * BM + r) * K + seg;
  const long bRow = (long)(bn * BN + r) * K + seg;

  const int lane = t & 63;
  const int w = t >> 6;
  const int wm = (w >> 1) * 64, wn = (w & 1) * 64;
  const int lc = lane & 15, quad = lane >> 4;

  floatx4 acc[4][4];
#pragma unroll
  for (int i = 0; i < 4; i++)
#pragma unroll
    for (int j = 0; j < 4; j++) acc[i][j] = (floatx4)0.f;

  float mr = 0.f;
  if (MODE == 3) mr = mrow[(long)bz * M + bm * BM + r];

  for (int kk = 0; kk < K; kk += BK) {
    uintx4 a0 = *(const uintx4*)(A + aRow + kk);
    uintx4 a1 = *(const uintx4*)(A + aRow + kk + 8);
    uintx4 b0 = *(const uintx4*)(Bm + bRow + kk);
    uintx4 b1 = *(const uintx4*)(Bm + bRow + kk + 8);
    if (MODE == 3) {
#pragma unroll
      for (int ii = 0; ii < 4; ii++) {
        {
          u32 xx = a0[ii];
          float lo = exp2f((b2f((u16)(xx & 0xffffu)) - mr) * LOG2E);
          float hi = exp2f((b2f((u16)(xx >> 16)) - mr) * LOG2E);
          a0[ii] = (u32)f2b(lo) | ((u32)f2b(hi) << 16);
        }
        {
          u32 xx = a1[ii];
          float lo = exp2f((b2f((u16)(xx & 0xffffu)) - mr) * LOG2E);
          float hi = exp2f((b2f((u16)(xx >> 16)) - mr) * LOG2E);
          a1[ii] = (u32)f2b(lo) | ((u32)f2b(hi) << 16);
        }
      }
    }
    __syncthreads();
    *(uintx4*)&As[r * LDT + seg]     = a0;
    *(uintx4*)&As[r * LDT + seg + 8] = a1;
    *(uintx4*)&Bs[r * LDT + seg]     = b0;
    *(uintx4*)&Bs[r * LDT + seg + 8] = b1;
    __syncthreads();

    short8 af[4], bfg[4];
#pragma unroll
    for (int i = 0; i < 4; i++)
      af[i] = *(const short8*)&As[(wm + i * 16 + lc) * LDT + quad * 8];
#pragma unroll
    for (int j = 0; j < 4; j++)
      bfg[j] = *(const short8*)&Bs[(wn + j * 16 + lc) * LDT + quad * 8];
#pragma unroll
    for (int i = 0; i < 4; i++)
#pragma unroll
      for (int j = 0; j < 4; j++)
        acc[i][j] = __builtin_amdgcn_mfma_f32_16x16x32_bf16(af[i], bfg[j], acc[i][j], 0, 0, 0);
  }

#pragma unroll
  for (int i = 0; i < 4; i++) {
    const int gm0 = bm * BM + wm + i * 16 + quad * 4;
#pragma unroll
    for (int j = 0; j < 4; j++) {
      const int gn = bn * BN + wn + j * 16 + lc;
      floatx4 a = acc[i][j];
      if (MODE == 0) {
        u16* Ou = (u16*)(Og + (long)bz * sO);
        const float bv = bias[gn];
#pragma unroll
        for (int rg = 0; rg < 4; rg++)
          Ou[(long)(gm0 + rg) * N + gn] = f2b(a[rg] + bv);
      } else if (MODE == 1) {
        u16* Ou = (u16*)(Og + (long)bz * sO);
        const float bv = bias[gn];
        short4v p;
#pragma unroll
        for (int rg = 0; rg < 4; rg++) p[rg] = (short)f2b(a[rg] + bv);
        *(short4v*)&Ou[(long)gn * M + gm0] = p;
      } else if (MODE == 2) {
        u16* Ou = (u16*)(Og + (long)bz * sO);
#pragma unroll
        for (int rg = 0; rg < 4; rg++)
          Ou[(long)(gm0 + rg) * N + gn] = f2b(a[rg] * 0.04419417382415922f);
      } else if (MODE == 3) {
        u16* Ou = (u16*)(Og + (long)bz * sO);
#pragma unroll
        for (int rg = 0; rg < 4; rg++)
          Ou[(long)(gm0 + rg) * N + gn] = f2b(a[rg] * rlrow[(long)bz * M + gm0 + rg]);
      } else {  // MODE 4: fp32 output + residual
        float* Of = (float*)Og + (long)bz * sO;
        const float bv = bias[gn];
        const float* Rz = resid + (long)bz * sR;
        const floatx4 rv = *(const floatx4*)&Rz[(long)gn * M + gm0];
        floatx4 p;
#pragma unroll
        for (int rg = 0; rg < 4; rg++) p[rg] = a[rg] + bv + rv[rg];
        *(floatx4*)&Of[(long)gn * M + gm0] = p;
      }
    }
  }
}

// ---------------------------------------------------------------- launch
extern "C" void kernel_launch(void* const* d_in, const int* in_sizes, int n_in,
                              void* d_out, int out_size, void* d_ws, size_t ws_size,
                              hipStream_t stream)
{
  const float* x  = (const float*)d_in[0];
  const float* gw = (const float*)d_in[1];
  const float* gb = (const float*)d_in[2];
  const float* wq = (const float*)d_in[3];
  const float* bq = (const float*)d_in[4];
  const float* wk = (const float*)d_in[5];
  const float* bk = (const float*)d_in[6];
  const float* wv = (const float*)d_in[7];
  const float* bv = (const float*)d_in[8];
  const float* wo = (const float*)d_in[9];
  const float* bo = (const float*)d_in[10];

  const long PB = (long)4096 * 512;        // per-batch token-matrix elems

  // ---- adaptive footprint: nB batches in flight, RS score-rows per pass ----
  auto need = [&](long nb, long rs) -> size_t {
    return (size_t)(4 * 262144 * 2           // bf16 weight copies
                  + nb * PB * 2 * 5          // h,q,k,vT,o (bf16)
                  + nb * rs * 4096 * 2       // S (bf16)
                  + nb * 4096 * 4 * 2        // mrow, rl (f32)
                  + 4096);                   // gm/gr + slack
  };
  const long cand_nB[4] = {8, 4, 2, 1};
  const long cand_RS[4] = {4096, 2048, 1024, 512};
  long nB = 1, RS = 512;
  bool found = false;
  for (int i = 0; i < 4 && !found; i++)
    for (int j = 0; j < 4 && !found; j++)
      if (need(cand_nB[i], cand_RS[j]) <= ws_size) { nB = cand_nB[i]; RS = cand_RS[j]; found = true; }

  char* ws = (char*)d_ws;
  u16*   wqb  = (u16*)ws;                      // 4 x 512x512 bf16
  u16*   wkb  = wqb + 262144;
  u16*   wvb  = wkb + 262144;
  u16*   wob  = wvb + 262144;
  bf16*  h    = (bf16*)(wob + 262144);
  bf16*  q    = h  + nB * PB;
  bf16*  k    = q  + nB * PB;
  bf16*  vT   = k  + nB * PB;
  bf16*  o    = vT + nB * PB;
  bf16*  S    = o  + nB * PB;                  // nB * RS * 4096 bf16
  float* mrow = (float*)(S + nB * RS * 4096);
  float* rl   = mrow + nB * 4096;
  float* gm   = rl + nB * 4096;                // 64 f32
  float* gr   = gm + 64;

  const long sS = RS * 4096;   // per-z S stride (elems)

  cvt_weights<<<dim3(256, 4), 256, 0, stream>>>(wq, wk, wv, wo, wqb, wkb, wvb, wob);
  gn_stats<<<dim3(8, 8), 256, 0, stream>>>(x, gm, gr);

  for (long b0 = 0; b0 < 8; b0 += nB) {
    const int gs = (int)nB;

    gn_apply<<<dim3(64, 8, gs), 256, 0, stream>>>(x + b0 * PB, gw, gb, gm + b0 * 8, gr + b0 * 8, h);

    gemm_bt<0><<<dim3(32, 4, gs), 256, 0, stream>>>(h, PB, (bf16*)wqb, 0, bq, nullptr, nullptr, nullptr, 0, q,  PB, 4096, 512, 512);
    gemm_bt<0><<<dim3(32, 4, gs), 256, 0, stream>>>(h, PB, (bf16*)wkb, 0, bk, nullptr, nullptr, nullptr, 0, k,  PB, 4096, 512, 512);
    gemm_bt<1><<<dim3(32, 4, gs), 256, 0, stream>>>(h, PB, (bf16*)wvb, 0, bv, nullptr, nullptr, nullptr, 0, vT, PB, 4096, 512, 512);

    for (long r0 = 0; r0 < 4096; r0 += RS) {
      gemm_bt<2><<<dim3((int)(RS / 128), 32, gs), 256, 0, stream>>>(
          q + r0 * 512, PB, k, PB,
          nullptr, nullptr, nullptr, nullptr, 0, S, sS, (int)RS, 4096, 512);
      row_stats<<<(int)(gs * RS), 256, 0, stream>>>(S, mrow, rl);
      gemm_bt<3><<<dim3((int)(RS / 128), 4, gs), 256, 0, stream>>>(
          S, sS, vT, PB,
          nullptr, mrow, rl, nullptr, 0, o + r0 * 512, PB, (int)RS, 512, 4096);
    }

    gemm_bt<4><<<dim3(32, 4, gs), 256, 0, stream>>>(o, PB, (bf16*)wob, 0, bo, nullptr, nullptr,
        x + b0 * PB, PB, (bf16*)((float*)d_out + b0 * PB), PB, 4096, 512, 512);
  }
}

// Round 4
// 1050.239 us; speedup vs baseline: 1.2095x; 1.2095x over previous
//
#include <hip/hip_runtime.h>
#include <hip/hip_bf16.h>
#include <stdint.h>

typedef __hip_bfloat16 bf16;
typedef unsigned short u16;
typedef unsigned int u32;
using short8  = __attribute__((ext_vector_type(8))) short;
using short4v = __attribute__((ext_vector_type(4))) short;
using floatx4 = __attribute__((ext_vector_type(4))) float;
using uintx4  = __attribute__((ext_vector_type(4))) u32;

#define LOG2E 1.44269504088896f

__device__ __forceinline__ float b2f(u16 u) {
  union { u32 i; float f; } v; v.i = ((u32)u) << 16; return v.f;
}
__device__ __forceinline__ u16 f2b(float f) {
  union { float f; u32 i; } v; v.f = f;
  u32 r = v.i + 0x7fffu + ((v.i >> 16) & 1u);
  return (u16)(r >> 16);
}

// async global->LDS, 16 B per lane; lds dest is wave-uniform base + lane*16
__device__ __forceinline__ void gl2lds16(const void* g, void* l) {
  __builtin_amdgcn_global_load_lds(
      (const __attribute__((address_space(1))) void*)g,
      (__attribute__((address_space(3))) void*)l,
      16, 0, 0);
}

// ------------------------------------------------ fp32 -> bf16 weight convert
__global__ __launch_bounds__(256)
void cvt_weights(const float* __restrict__ w0, const float* __restrict__ w1,
                 const float* __restrict__ w2, const float* __restrict__ w3,
                 u16* __restrict__ o0, u16* __restrict__ o1,
                 u16* __restrict__ o2, u16* __restrict__ o3)
{
  const float* w = blockIdx.y == 0 ? w0 : blockIdx.y == 1 ? w1 : blockIdx.y == 2 ? w2 : w3;
  u16* o = blockIdx.y == 0 ? o0 : blockIdx.y == 1 ? o1 : blockIdx.y == 2 ? o2 : o3;
  const int i = (blockIdx.x * 256 + threadIdx.x) * 4;
  floatx4 v = *(const floatx4*)(w + i);
  short4v p;
#pragma unroll
  for (int j = 0; j < 4; j++) p[j] = (short)f2b(v[j]);
  *(short4v*)(o + i) = p;
}

// ---------------------------------------------------------------- GroupNorm
__global__ __launch_bounds__(256)
void gn_stats(const float* __restrict__ x, float* __restrict__ gmean, float* __restrict__ grstd)
{
  const int g = blockIdx.x, b = blockIdx.y;
  const float* base = x + ((long)(b * 512 + g * 64)) * 4096;
  const int t = threadIdx.x;
  float s = 0.f, ss = 0.f;
  for (int i = 0; i < 256; i++) {
    floatx4 v = *(const floatx4*)(base + i * 1024 + t * 4);
#pragma unroll
    for (int j = 0; j < 4; j++) { s += v[j]; ss += v[j] * v[j]; }
  }
  for (int off = 1; off < 64; off <<= 1) {
    s  += __shfl_xor(s, off, 64);
    ss += __shfl_xor(ss, off, 64);
  }
  __shared__ float as_[4], ass_[4];
  if ((t & 63) == 0) { as_[t >> 6] = s; ass_[t >> 6] = ss; }
  __syncthreads();
  if (t == 0) {
    float S1 = as_[0] + as_[1] + as_[2] + as_[3];
    float S2 = ass_[0] + ass_[1] + ass_[2] + ass_[3];
    const float inv = 1.0f / 262144.0f;
    float mu = S1 * inv;
    float var = S2 * inv - mu * mu;
    gmean[b * 8 + g] = mu;
    grstd[b * 8 + g] = rsqrtf(var + 1e-5f);
  }
}

// normalize + transpose: x[b][c][p] (fp32) -> h[b][p][c] (bf16); b chunk-local
__global__ __launch_bounds__(256)
void gn_apply(const float* __restrict__ x, const float* __restrict__ gw, const float* __restrict__ gb,
              const float* __restrict__ gmean, const float* __restrict__ grstd,
              bf16* __restrict__ h)
{
  const int b = blockIdx.z;
  const int c0 = blockIdx.y * 64;
  const int p0 = blockIdx.x * 64;
  const int t = threadIdx.x;
  const int c = c0 + (t & 63);
  const int g = c >> 6;
  const float mu = gmean[b * 8 + g], rs = grstd[b * 8 + g];
  const float wv = gw[c];
  const float bv = gb[c];
  const float a = rs * wv;
  const float bb = bv - mu * rs * wv;
  const float* xp = x + ((long)(b * 512 + c)) * 4096;
  u16* hp = (u16*)h + ((long)b * 4096) * 512 + c;
  const int pbase = p0 + (t >> 6);
#pragma unroll
  for (int i = 0; i < 16; i++) {
    int p = pbase + i * 4;
    float xv = xp[p];
    hp[(long)p * 512] = f2b(xv * a + bb);
  }
}

// ---------------------------------------------- softmax stats + P materialize
// one block per S row: computes m, writes P = exp(s-m) in place, rl = 1/sum
__global__ __launch_bounds__(256)
void row_stats(bf16* __restrict__ S, float* __restrict__ rl)
{
  const long row = blockIdx.x;
  const int t = threadIdx.x;
  u16* Sr = (u16*)S + row * 4096;
  uintx4 v0 = *(const uintx4*)(Sr + t * 16);
  uintx4 v1 = *(const uintx4*)(Sr + t * 16 + 8);
  float vals[16];
#pragma unroll
  for (int i = 0; i < 4; i++) {
    vals[2 * i]         = b2f((u16)(v0[i] & 0xffffu));
    vals[2 * i + 1]     = b2f((u16)(v0[i] >> 16));
    vals[8 + 2 * i]     = b2f((u16)(v1[i] & 0xffffu));
    vals[8 + 2 * i + 1] = b2f((u16)(v1[i] >> 16));
  }
  float m = vals[0];
#pragma unroll
  for (int i = 1; i < 16; i++) m = fmaxf(m, vals[i]);
  for (int off = 1; off < 64; off <<= 1) m = fmaxf(m, __shfl_xor(m, off, 64));
  __shared__ float sm[4], st[4];
  if ((t & 63) == 0) sm[t >> 6] = m;
  __syncthreads();
  m = fmaxf(fmaxf(sm[0], sm[1]), fmaxf(sm[2], sm[3]));
  float pe[16];
  float s = 0.f;
#pragma unroll
  for (int i = 0; i < 16; i++) { pe[i] = exp2f((vals[i] - m) * LOG2E); s += pe[i]; }
  for (int off = 1; off < 64; off <<= 1) s += __shfl_xor(s, off, 64);
  if ((t & 63) == 0) st[t >> 6] = s;
  // write P back in place (bf16)
  uintx4 w0, w1;
#pragma unroll
  for (int i = 0; i < 4; i++) {
    w0[i] = (u32)f2b(pe[2 * i])     | ((u32)f2b(pe[2 * i + 1]) << 16);
    w1[i] = (u32)f2b(pe[8 + 2 * i]) | ((u32)f2b(pe[8 + 2 * i + 1]) << 16);
  }
  *(uintx4*)(Sr + t * 16)     = w0;
  *(uintx4*)(Sr + t * 16 + 8) = w1;
  __syncthreads();
  if (t == 0) {
    float tot = st[0] + st[1] + st[2] + st[3];
    rl[row] = 1.0f / tot;
  }
}

// ---------------------------------------------------------------- GEMM: C = A @ B^T
// A,B bf16 (row-major, K contiguous). bias/resid fp32.
// MODE 0: +bias, write bf16 out[m][n]                  (Q, K)
// MODE 1: +bias, write bf16 out[n][m]                  (V -> vT)
// MODE 2: *1/sqrt(512), write bf16 out[m][n]           (S = q k^T)
// MODE 3: epilogue *1/l, write bf16 out[m][n]          (O = P V)
// MODE 4: +bias + residual, write FP32 out[n][m]       (final proj + x)
constexpr int BM = 128, BN = 128, BK = 32;

template<int MODE>
__global__ __launch_bounds__(256)
void gemm_bt(const bf16* __restrict__ Ag, long sA,
             const bf16* __restrict__ Bg, long sB,
             const float* __restrict__ bias,
             const float* __restrict__ rlrow,
             const float* __restrict__ resid, long sR,
             bf16* __restrict__ Og, long sO,
             int M, int N, int K)
{
  __shared__ u16 As[BM * BK];   // 128 rows x 32 bf16, 64 B/row, unpadded
  __shared__ u16 Bs[BN * BK];
  const int t = threadIdx.x;
  const int bz = blockIdx.z;
  const u16* A = (const u16*)Ag + (long)bz * sA;
  const u16* B = (const u16*)Bg + (long)bz * sB;

  const int bm = blockIdx.x, bn = blockIdx.y;
  const int lane = t & 63, w = t >> 6;

  // staging: each lane loads 16 B; wave w covers rows [w*16, w*16+16) and +64
  const int rs = w * 16 + (lane >> 2);
  const int sg = (lane & 3) * 8;
  const long aOff  = (long)(bm * BM + rs) * K + sg;
  const long bOff  = (long)(bn * BN + rs) * K + sg;
  const long aOff2 = aOff + (long)64 * K;
  const long bOff2 = bOff + (long)64 * K;
  char* asw = (char*)As + w * 1024;
  char* bsw = (char*)Bs + w * 1024;

  const int wm = (w >> 1) * 64, wn = (w & 1) * 64;
  const int lc = lane & 15, quad = lane >> 4;

  floatx4 acc[4][4];
#pragma unroll
  for (int i = 0; i < 4; i++)
#pragma unroll
    for (int j = 0; j < 4; j++) acc[i][j] = (floatx4)0.f;

  for (int kk = 0; kk < K; kk += BK) {
    __syncthreads();
    gl2lds16(A + aOff + kk,  asw);
    gl2lds16(A + aOff2 + kk, asw + 4096);
    gl2lds16(B + bOff + kk,  bsw);
    gl2lds16(B + bOff2 + kk, bsw + 4096);
    __syncthreads();

    short8 af[4], bfr[4];
#pragma unroll
    for (int i = 0; i < 4; i++)
      af[i] = *(const short8*)&As[(wm + i * 16 + lc) * BK + quad * 8];
#pragma unroll
    for (int j = 0; j < 4; j++)
      bfr[j] = *(const short8*)&Bs[(wn + j * 16 + lc) * BK + quad * 8];
#pragma unroll
    for (int i = 0; i < 4; i++)
#pragma unroll
      for (int j = 0; j < 4; j++)
        acc[i][j] = __builtin_amdgcn_mfma_f32_16x16x32_bf16(af[i], bfr[j], acc[i][j], 0, 0, 0);
  }

#pragma unroll
  for (int i = 0; i < 4; i++) {
    const int gm0 = bm * BM + wm + i * 16 + quad * 4;
#pragma unroll
    for (int j = 0; j < 4; j++) {
      const int gn = bn * BN + wn + j * 16 + lc;
      floatx4 a = acc[i][j];
      if (MODE == 0) {
        u16* Ou = (u16*)(Og + (long)bz * sO);
        const float bv = bias[gn];
#pragma unroll
        for (int rg = 0; rg < 4; rg++)
          Ou[(long)(gm0 + rg) * N + gn] = f2b(a[rg] + bv);
      } else if (MODE == 1) {
        u16* Ou = (u16*)(Og + (long)bz * sO);
        const float bv = bias[gn];
        short4v p;
#pragma unroll
        for (int rg = 0; rg < 4; rg++) p[rg] = (short)f2b(a[rg] + bv);
        *(short4v*)&Ou[(long)gn * M + gm0] = p;
      } else if (MODE == 2) {
        u16* Ou = (u16*)(Og + (long)bz * sO);
#pragma unroll
        for (int rg = 0; rg < 4; rg++)
          Ou[(long)(gm0 + rg) * N + gn] = f2b(a[rg] * 0.04419417382415922f);
      } else if (MODE == 3) {
        u16* Ou = (u16*)(Og + (long)bz * sO);
#pragma unroll
        for (int rg = 0; rg < 4; rg++)
          Ou[(long)(gm0 + rg) * N + gn] = f2b(a[rg] * rlrow[(long)bz * M + gm0 + rg]);
      } else {  // MODE 4: fp32 output + residual, transposed
        float* Of = (float*)Og + (long)bz * sO;
        const float bv = bias[gn];
        const float* Rz = resid + (long)bz * sR;
        const floatx4 rv = *(const floatx4*)&Rz[(long)gn * M + gm0];
        floatx4 p;
#pragma unroll
        for (int rg = 0; rg < 4; rg++) p[rg] = a[rg] + bv + rv[rg];
        *(floatx4*)&Of[(long)gn * M + gm0] = p;
      }
    }
  }
}

// ---------------------------------------------------------------- launch
extern "C" void kernel_launch(void* const* d_in, const int* in_sizes, int n_in,
                              void* d_out, int out_size, void* d_ws, size_t ws_size,
                              hipStream_t stream)
{
  const float* x  = (const float*)d_in[0];
  const float* gw = (const float*)d_in[1];
  const float* gb = (const float*)d_in[2];
  const float* wq = (const float*)d_in[3];
  const float* bq = (const float*)d_in[4];
  const float* wk = (const float*)d_in[5];
  const float* bk = (const float*)d_in[6];
  const float* wv = (const float*)d_in[7];
  const float* bv = (const float*)d_in[8];
  const float* wo = (const float*)d_in[9];
  const float* bo = (const float*)d_in[10];

  const long PB = (long)4096 * 512;        // per-batch token-matrix elems

  auto need = [&](long nb, long rs) -> size_t {
    return (size_t)(4 * 262144 * 2           // bf16 weight copies
                  + nb * PB * 2 * 5          // h,q,k,vT,o (bf16)
                  + nb * rs * 4096 * 2       // S (bf16)
                  + nb * 4096 * 4 * 2        // mrow, rl (f32)
                  + 4096);
  };
  const long cand_nB[4] = {8, 4, 2, 1};
  const long cand_RS[4] = {4096, 2048, 1024, 512};
  long nB = 1, RS = 512;
  bool found = false;
  for (int i = 0; i < 4 && !found; i++)
    for (int j = 0; j < 4 && !found; j++)
      if (need(cand_nB[i], cand_RS[j]) <= ws_size) { nB = cand_nB[i]; RS = cand_RS[j]; found = true; }

  char* ws = (char*)d_ws;
  u16*   wqb  = (u16*)ws;
  u16*   wkb  = wqb + 262144;
  u16*   wvb  = wkb + 262144;
  u16*   wob  = wvb + 262144;
  bf16*  h    = (bf16*)(wob + 262144);
  bf16*  q    = h  + nB * PB;
  bf16*  k    = q  + nB * PB;
  bf16*  vT   = k  + nB * PB;
  bf16*  o    = vT + nB * PB;
  bf16*  S    = o  + nB * PB;
  float* mrow = (float*)(S + nB * RS * 4096);
  float* rl   = mrow + nB * 4096;
  float* gm   = rl + nB * 4096;
  float* gr   = gm + 64;
  (void)mrow;

  const long sS = RS * 4096;

  cvt_weights<<<dim3(256, 4), 256, 0, stream>>>(wq, wk, wv, wo, wqb, wkb, wvb, wob);
  gn_stats<<<dim3(8, 8), 256, 0, stream>>>(x, gm, gr);

  for (long b0 = 0; b0 < 8; b0 += nB) {
    const int gs = (int)nB;

    gn_apply<<<dim3(64, 8, gs), 256, 0, stream>>>(x + b0 * PB, gw, gb, gm + b0 * 8, gr + b0 * 8, h);

    gemm_bt<0><<<dim3(32, 4, gs), 256, 0, stream>>>(h, PB, (bf16*)wqb, 0, bq, nullptr, nullptr, 0, q,  PB, 4096, 512, 512);
    gemm_bt<0><<<dim3(32, 4, gs), 256, 0, stream>>>(h, PB, (bf16*)wkb, 0, bk, nullptr, nullptr, 0, k,  PB, 4096, 512, 512);
    gemm_bt<1><<<dim3(32, 4, gs), 256, 0, stream>>>(h, PB, (bf16*)wvb, 0, bv, nullptr, nullptr, 0, vT, PB, 4096, 512, 512);

    for (long r0 = 0; r0 < 4096; r0 += RS) {
      gemm_bt<2><<<dim3((int)(RS / 128), 32, gs), 256, 0, stream>>>(
          q + r0 * 512, PB, k, PB,
          nullptr, nullptr, nullptr, 0, S, sS, (int)RS, 4096, 512);
      row_stats<<<(int)(gs * RS), 256, 0, stream>>>(S, rl);
      gemm_bt<3><<<dim3((int)(RS / 128), 4, gs), 256, 0, stream>>>(
          S, sS, vT, PB,
          nullptr, rl, nullptr, 0, o + r0 * 512, PB, (int)RS, 512, 4096);
    }

    gemm_bt<4><<<dim3(32, 4, gs), 256, 0, stream>>>(o, PB, (bf16*)wob, 0, bo, nullptr,
        x + b0 * PB, PB, (bf16*)((float*)d_out + b0 * PB), PB, 4096, 512, 512);
  }
}

// Round 5
// 858.184 us; speedup vs baseline: 1.4802x; 1.2238x over previous
//
#include <hip/hip_runtime.h>
#include <hip/hip_bf16.h>
#include <stdint.h>

typedef __hip_bfloat16 bf16;
typedef unsigned short u16;
typedef unsigned int u32;
using short8  = __attribute__((ext_vector_type(8))) short;
using short4v = __attribute__((ext_vector_type(4))) short;
using floatx4 = __attribute__((ext_vector_type(4))) float;
using uintx4  = __attribute__((ext_vector_type(4))) u32;

#define LOG2E 1.44269504088896f

__device__ __forceinline__ float b2f(u16 u) {
  union { u32 i; float f; } v; v.i = ((u32)u) << 16; return v.f;
}
__device__ __forceinline__ u16 f2b(float f) {
  union { float f; u32 i; } v; v.f = f;
  u32 r = v.i + 0x7fffu + ((v.i >> 16) & 1u);
  return (u16)(r >> 16);
}

__device__ __forceinline__ void gl2lds16(const void* g, void* l) {
  __builtin_amdgcn_global_load_lds(
      (const __attribute__((address_space(1))) void*)g,
      (__attribute__((address_space(3))) void*)l,
      16, 0, 0);
}

// ------------------------------------------------ fp32 -> bf16 weight convert
__global__ __launch_bounds__(256)
void cvt_weights(const float* __restrict__ w0, const float* __restrict__ w1,
                 const float* __restrict__ w2, const float* __restrict__ w3,
                 u16* __restrict__ o0, u16* __restrict__ o1,
                 u16* __restrict__ o2, u16* __restrict__ o3)
{
  const float* w = blockIdx.y == 0 ? w0 : blockIdx.y == 1 ? w1 : blockIdx.y == 2 ? w2 : w3;
  u16* o = blockIdx.y == 0 ? o0 : blockIdx.y == 1 ? o1 : blockIdx.y == 2 ? o2 : o3;
  const int i = (blockIdx.x * 256 + threadIdx.x) * 4;
  floatx4 v = *(const floatx4*)(w + i);
  short4v p;
#pragma unroll
  for (int j = 0; j < 4; j++) p[j] = (short)f2b(v[j]);
  *(short4v*)(o + i) = p;
}

// ---------------------------------------------------------------- GroupNorm
__global__ __launch_bounds__(256)
void gn_stats(const float* __restrict__ x, float* __restrict__ gmean, float* __restrict__ grstd)
{
  const int g = blockIdx.x, b = blockIdx.y;
  const float* base = x + ((long)(b * 512 + g * 64)) * 4096;
  const int t = threadIdx.x;
  float s = 0.f, ss = 0.f;
  for (int i = 0; i < 256; i++) {
    floatx4 v = *(const floatx4*)(base + i * 1024 + t * 4);
#pragma unroll
    for (int j = 0; j < 4; j++) { s += v[j]; ss += v[j] * v[j]; }
  }
  for (int off = 1; off < 64; off <<= 1) {
    s  += __shfl_xor(s, off, 64);
    ss += __shfl_xor(ss, off, 64);
  }
  __shared__ float as_[4], ass_[4];
  if ((t & 63) == 0) { as_[t >> 6] = s; ass_[t >> 6] = ss; }
  __syncthreads();
  if (t == 0) {
    float S1 = as_[0] + as_[1] + as_[2] + as_[3];
    float S2 = ass_[0] + ass_[1] + ass_[2] + ass_[3];
    const float inv = 1.0f / 262144.0f;
    float mu = S1 * inv;
    float var = S2 * inv - mu * mu;
    gmean[b * 8 + g] = mu;
    grstd[b * 8 + g] = rsqrtf(var + 1e-5f);
  }
}

// normalize + transpose: x[b][c][p] (fp32) -> h[b][p][c] (bf16); b chunk-local
__global__ __launch_bounds__(256)
void gn_apply(const float* __restrict__ x, const float* __restrict__ gw, const float* __restrict__ gb,
              const float* __restrict__ gmean, const float* __restrict__ grstd,
              bf16* __restrict__ h)
{
  const int b = blockIdx.z;
  const int c0 = blockIdx.y * 64;
  const int p0 = blockIdx.x * 64;
  const int t = threadIdx.x;
  const int c = c0 + (t & 63);
  const int g = c >> 6;
  const float mu = gmean[b * 8 + g], rs = grstd[b * 8 + g];
  const float wv = gw[c];
  const float bv = gb[c];
  const float a = rs * wv;
  const float bb = bv - mu * rs * wv;
  const float* xp = x + ((long)(b * 512 + c)) * 4096;
  u16* hp = (u16*)h + ((long)b * 4096) * 512 + c;
  const int pbase = p0 + (t >> 6);
#pragma unroll
  for (int i = 0; i < 16; i++) {
    int p = pbase + i * 4;
    float xv = xp[p];
    hp[(long)p * 512] = f2b(xv * a + bb);
  }
}

// ---------------------------------------------- softmax stats + P materialize
__global__ __launch_bounds__(256)
void row_stats(bf16* __restrict__ S, float* __restrict__ rl)
{
  const long row = blockIdx.x;
  const int t = threadIdx.x;
  u16* Sr = (u16*)S + row * 4096;
  uintx4 v0 = *(const uintx4*)(Sr + t * 16);
  uintx4 v1 = *(const uintx4*)(Sr + t * 16 + 8);
  float vals[16];
#pragma unroll
  for (int i = 0; i < 4; i++) {
    vals[2 * i]         = b2f((u16)(v0[i] & 0xffffu));
    vals[2 * i + 1]     = b2f((u16)(v0[i] >> 16));
    vals[8 + 2 * i]     = b2f((u16)(v1[i] & 0xffffu));
    vals[8 + 2 * i + 1] = b2f((u16)(v1[i] >> 16));
  }
  float m = vals[0];
#pragma unroll
  for (int i = 1; i < 16; i++) m = fmaxf(m, vals[i]);
  for (int off = 1; off < 64; off <<= 1) m = fmaxf(m, __shfl_xor(m, off, 64));
  __shared__ float sm[4], st[4];
  if ((t & 63) == 0) sm[t >> 6] = m;
  __syncthreads();
  m = fmaxf(fmaxf(sm[0], sm[1]), fmaxf(sm[2], sm[3]));
  float pe[16];
  float s = 0.f;
#pragma unroll
  for (int i = 0; i < 16; i++) { pe[i] = exp2f((vals[i] - m) * LOG2E); s += pe[i]; }
  for (int off = 1; off < 64; off <<= 1) s += __shfl_xor(s, off, 64);
  if ((t & 63) == 0) st[t >> 6] = s;
  uintx4 w0, w1;
#pragma unroll
  for (int i = 0; i < 4; i++) {
    w0[i] = (u32)f2b(pe[2 * i])     | ((u32)f2b(pe[2 * i + 1]) << 16);
    w1[i] = (u32)f2b(pe[8 + 2 * i]) | ((u32)f2b(pe[8 + 2 * i + 1]) << 16);
  }
  *(uintx4*)(Sr + t * 16)     = w0;
  *(uintx4*)(Sr + t * 16 + 8) = w1;
  __syncthreads();
  if (t == 0) {
    float tot = st[0] + st[1] + st[2] + st[3];
    rl[row] = 1.0f / tot;
  }
}

// ------------------------------------------------ split-K PV partial reduce
// o[z][m][d] = (sum_sp part[z][sp][m][d]) * rl[z*RS+m]  (bf16 out)
__global__ __launch_bounds__(256)
void pv_reduce(const bf16* __restrict__ part, const float* __restrict__ rl,
               bf16* __restrict__ o, long sOz, int RS)
{
  const int z = blockIdx.x;
  const long base = (long)blockIdx.y * 1024 + threadIdx.x * 4;
  const long slab = (long)RS * 512;
  const u16* p = (const u16*)part + (long)z * 4 * slab + base;
  floatx4 s = (floatx4)0.f;
#pragma unroll
  for (int sp = 0; sp < 4; sp++) {
    short4v v = *(const short4v*)(p + sp * slab);
#pragma unroll
    for (int j = 0; j < 4; j++) s[j] += b2f((u16)v[j]);
  }
  const float r = rl[z * RS + (int)(base >> 9)];
  short4v ov;
#pragma unroll
  for (int j = 0; j < 4; j++) ov[j] = (short)f2b(s[j] * r);
  *(short4v*)((u16*)o + (long)z * sOz + base) = ov;
}

// ---------------------------------------------------------------- GEMM: C = A @ B^T
// blockIdx.x = z (XCD affinity), .y = M-tile, .z = N-tile (MODE3: N-tile + split)
// MODE 0: +bias, bf16 out[m][n]              (Q, K proj)
// MODE 1: +bias, bf16 out[n][m]              (V -> vT)
// MODE 2: *1/sqrt(512), bf16 out[m][n]       (S = q k^T)
// MODE 3: split-K x4, bf16 partial out       (P V partials)
// MODE 4: +bias+residual, fp32 out[n][m]     (final proj + x)
constexpr int BM = 128, BN = 128, BK = 32;

template<int MODE>
__global__ __launch_bounds__(256)
void gemm_bt(const bf16* __restrict__ Ag, long sA,
             const bf16* __restrict__ Bg, long sB,
             const float* __restrict__ bias,
             const float* __restrict__ resid, long sR,
             bf16* __restrict__ Og, long sO,
             int M, int N, int K)
{
  __shared__ u16 As[2][BM * BK];
  __shared__ u16 Bs[2][BN * BK];
  const int t = threadIdx.x;
  const int bz = blockIdx.x;
  const int bm = blockIdx.y;
  int bn = blockIdx.z, sp = 0, kbeg = 0, kend = K;
  if (MODE == 3) { sp = bn >> 2; bn &= 3; kbeg = sp * 1024; kend = kbeg + 1024; }

  const u16* A = (const u16*)Ag + (long)bz * sA;
  const u16* B = (const u16*)Bg + (long)bz * sB;

  const int lane = t & 63, w = t >> 6;

  // staging: lane -> row rs_=w*16+(lane>>2), swizzled 16B segment
  const int rs_ = w * 16 + (lane >> 2);
  const int seg = ((lane & 3) ^ ((rs_ >> 1) & 3)) * 8;   // elems
  const long aOff  = (long)(bm * BM + rs_) * K + seg;
  const long bOff  = (long)(bn * BN + rs_) * K + seg;
  const long aOff2 = aOff + 64L * K;   // (rs_+64)>>1 & 3 == rs_>>1 & 3, same seg
  const long bOff2 = bOff + 64L * K;
  const int wofs = w * 1024;           // bytes within 8KB tile

  const int wm = (w >> 1) * 64, wn = (w & 1) * 64;
  const int lc = lane & 15, quad = lane >> 4;

  // hoisted swizzled ds_read offsets (bytes within 8KB tile)
  int aoffs[4], boffs[4];
#pragma unroll
  for (int i = 0; i < 4; i++) {
    const int Ra = wm + i * 16 + lc;
    const int Rb = wn + i * 16 + lc;
    aoffs[i] = Ra * 64 + ((quad ^ ((Ra >> 1) & 3)) * 16);
    boffs[i] = Rb * 64 + ((quad ^ ((Rb >> 1) & 3)) * 16);
  }

  floatx4 acc[4][4];
#pragma unroll
  for (int i = 0; i < 4; i++)
#pragma unroll
    for (int j = 0; j < 4; j++) acc[i][j] = (floatx4)0.f;

  auto stage = [&](int buf, int kk) {
    char* aw = (char*)&As[buf][0] + wofs;
    char* bw = (char*)&Bs[buf][0] + wofs;
    gl2lds16(A + aOff  + kk, aw);
    gl2lds16(A + aOff2 + kk, aw + 4096);
    gl2lds16(B + bOff  + kk, bw);
    gl2lds16(B + bOff2 + kk, bw + 4096);
  };

  stage(0, kbeg);
  int cur = 0;
  for (int kk = kbeg; kk < kend; kk += BK) {
    __syncthreads();
    if (kk + BK < kend) stage(cur ^ 1, kk + BK);
    const char* Ac = (const char*)&As[cur][0];
    const char* Bc = (const char*)&Bs[cur][0];
    short8 af[4], bfr[4];
#pragma unroll
    for (int i = 0; i < 4; i++) af[i]  = *(const short8*)(Ac + aoffs[i]);
#pragma unroll
    for (int j = 0; j < 4; j++) bfr[j] = *(const short8*)(Bc + boffs[j]);
#pragma unroll
    for (int i = 0; i < 4; i++)
#pragma unroll
      for (int j = 0; j < 4; j++)
        acc[i][j] = __builtin_amdgcn_mfma_f32_16x16x32_bf16(af[i], bfr[j], acc[i][j], 0, 0, 0);
    cur ^= 1;
  }

#pragma unroll
  for (int i = 0; i < 4; i++) {
    const int gm0 = bm * BM + wm + i * 16 + quad * 4;
#pragma unroll
    for (int j = 0; j < 4; j++) {
      const int gn = bn * BN + wn + j * 16 + lc;
      floatx4 a = acc[i][j];
      if (MODE == 0) {
        u16* Ou = (u16*)(Og + (long)bz * sO);
        const float bv = bias[gn];
#pragma unroll
        for (int rg = 0; rg < 4; rg++)
          Ou[(long)(gm0 + rg) * N + gn] = f2b(a[rg] + bv);
      } else if (MODE == 1) {
        u16* Ou = (u16*)(Og + (long)bz * sO);
        const float bv = bias[gn];
        short4v p;
#pragma unroll
        for (int rg = 0; rg < 4; rg++) p[rg] = (short)f2b(a[rg] + bv);
        *(short4v*)&Ou[(long)gn * M + gm0] = p;
      } else if (MODE == 2) {
        u16* Ou = (u16*)(Og + (long)bz * sO);
#pragma unroll
        for (int rg = 0; rg < 4; rg++)
          Ou[(long)(gm0 + rg) * N + gn] = f2b(a[rg] * 0.04419417382415922f);
      } else if (MODE == 3) {
        u16* Ou = (u16*)Og + (long)(bz * 4 + sp) * sO;
#pragma unroll
        for (int rg = 0; rg < 4; rg++)
          Ou[(long)(gm0 + rg) * N + gn] = f2b(a[rg]);
      } else {  // MODE 4: fp32 out + residual, transposed
        float* Of = (float*)Og + (long)bz * sO;
        const float bv = bias[gn];
        const float* Rz = resid + (long)bz * sR;
        const floatx4 rv = *(const floatx4*)&Rz[(long)gn * M + gm0];
        floatx4 p;
#pragma unroll
        for (int rg = 0; rg < 4; rg++) p[rg] = a[rg] + bv + rv[rg];
        *(floatx4*)&Of[(long)gn * M + gm0] = p;
      }
    }
  }
}

// ---------------------------------------------------------------- launch
extern "C" void kernel_launch(void* const* d_in, const int* in_sizes, int n_in,
                              void* d_out, int out_size, void* d_ws, size_t ws_size,
                              hipStream_t stream)
{
  const float* x  = (const float*)d_in[0];
  const float* gw = (const float*)d_in[1];
  const float* gb = (const float*)d_in[2];
  const float* wq = (const float*)d_in[3];
  const float* bq = (const float*)d_in[4];
  const float* wk = (const float*)d_in[5];
  const float* bk = (const float*)d_in[6];
  const float* wv = (const float*)d_in[7];
  const float* bv = (const float*)d_in[8];
  const float* wo = (const float*)d_in[9];
  const float* bo = (const float*)d_in[10];

  const long PB = (long)4096 * 512;

  // footprint: weights + h(=o),q,k,vT + S + bf16 partials(x4) + rl + stats
  auto need = [&](long nb, long rs) -> size_t {
    return (size_t)(4 * 262144 * 2
                  + nb * PB * 2 * 4
                  + nb * rs * 4096 * 2
                  + nb * 4 * rs * 512 * 2
                  + nb * 4096 * 4
                  + 8192);
  };
  const long cand_nB[4] = {8, 4, 2, 1};
  const long cand_RS[2] = {1024, 512};
  long nB = 1, RS = 512;
  bool found = false;
  for (int i = 0; i < 4 && !found; i++)
    for (int j = 0; j < 2 && !found; j++)
      if (need(cand_nB[i], cand_RS[j]) <= ws_size) { nB = cand_nB[i]; RS = cand_RS[j]; found = true; }

  char* ws = (char*)d_ws;
  u16*   wqb  = (u16*)ws;
  u16*   wkb  = wqb + 262144;
  u16*   wvb  = wkb + 262144;
  u16*   wob  = wvb + 262144;
  bf16*  h    = (bf16*)(wob + 262144);
  bf16*  q    = h  + nB * PB;
  bf16*  k    = q  + nB * PB;
  bf16*  vT   = k  + nB * PB;
  bf16*  o    = h;                       // reuse: h dead after V-proj
  bf16*  S    = vT + nB * PB;
  bf16*  part = S + nB * RS * 4096;      // nB*4*RS*512 bf16
  float* rl   = (float*)(part + nB * 4 * RS * 512);
  float* gm   = rl + nB * 4096;
  float* gr   = gm + 64;

  const long sS = RS * 4096;

  cvt_weights<<<dim3(256, 4), 256, 0, stream>>>(wq, wk, wv, wo, wqb, wkb, wvb, wob);
  gn_stats<<<dim3(8, 8), 256, 0, stream>>>(x, gm, gr);

  for (long b0 = 0; b0 < 8; b0 += nB) {
    const int gs = (int)nB;

    gn_apply<<<dim3(64, 8, gs), 256, 0, stream>>>(x + b0 * PB, gw, gb, gm + b0 * 8, gr + b0 * 8, h);

    gemm_bt<0><<<dim3(gs, 32, 4), 256, 0, stream>>>(h, PB, (bf16*)wqb, 0, bq, nullptr, 0, q,  PB, 4096, 512, 512);
    gemm_bt<0><<<dim3(gs, 32, 4), 256, 0, stream>>>(h, PB, (bf16*)wkb, 0, bk, nullptr, 0, k,  PB, 4096, 512, 512);
    gemm_bt<1><<<dim3(gs, 32, 4), 256, 0, stream>>>(h, PB, (bf16*)wvb, 0, bv, nullptr, 0, vT, PB, 4096, 512, 512);

    for (long r0 = 0; r0 < 4096; r0 += RS) {
      gemm_bt<2><<<dim3(gs, (int)(RS / 128), 32), 256, 0, stream>>>(
          q + r0 * 512, PB, k, PB, nullptr, nullptr, 0,
          S, sS, (int)RS, 4096, 512);
      row_stats<<<(int)(gs * RS), 256, 0, stream>>>(S, rl);
      gemm_bt<3><<<dim3(gs, (int)(RS / 128), 16), 256, 0, stream>>>(
          S, sS, vT, PB, nullptr, nullptr, 0,
          part, (long)RS * 512, (int)RS, 512, 4096);
      pv_reduce<<<dim3(gs, (int)(RS / 2)), 256, 0, stream>>>(
          part, rl, o + r0 * 512, PB, (int)RS);
    }

    gemm_bt<4><<<dim3(gs, 32, 4), 256, 0, stream>>>(o, PB, (bf16*)wob, 0, bo,
        x + b0 * PB, PB, (bf16*)((float*)d_out + b0 * PB), PB, 4096, 512, 512);
  }
}